// Round 2
// baseline (5613.995 us; speedup 1.0000x reference)
//
#include <hip/hip_runtime.h>
#include <hip/hip_bf16.h>

// Problem constants
#define BATCH 32
#define TLEN 512
#define INCH 512
#define HID 512
#define GATES 2048   // 4*HID
#define MTOT 4096    // both directions' gate rows

typedef __bf16 bf16x8 __attribute__((ext_vector_type(8)));
typedef float f32x4 __attribute__((ext_vector_type(4)));
using bf16 = __hip_bfloat16;

// ---------------- ws layout (bytes) ----------------
#define OFF_XS2   0ull                      // 16384*512*2 = 16 MiB
#define OFF_WCAT  16777216ull               // 4096*512*2  = 4 MiB
#define OFF_WHHP  20971520ull               // 2*2048*512*2 = 4 MiB
#define OFF_BIAS  25165824ull               // 2*2048*4 = 16 KiB
#define OFF_HBUF  25182208ull               // 2dir*2buf*32*512*2 = 128 KiB
#define OFF_CTR   25313280ull               // 256 B
#define OFF_XP    25313536ull               // 512*2*2048*32*2 = 128 MiB
#define WS_REQUIRED (25313536ull + 134217728ull)   // 159,531,264 B ≈ 152.2 MiB

__device__ __forceinline__ float sigmoid_fast(float x) {
    return 1.f / (1.f + __expf(-x));
}
__device__ __forceinline__ float tanh_fast(float x) {
    float ax = fabsf(x);
    float e = __expf(-2.f * ax);
    float r = (1.f - e) / (1.f + e);
    return copysignf(r, x);
}

// diagnosable failure marker: ws too small
__global__ void ws_too_small_kernel(float* out) {
    if (threadIdx.x == 0 && blockIdx.x == 0) out[0] = 12345.0f;
}

// ---------------- pack x -> XS2[(t*32+b)][k] bf16 ----------------
// x: [32][32][16][512] f32 ; k = c*16+h ; LDS transpose per (b, t-tile, k-tile)
__global__ void pack_x_kernel(const float* __restrict__ x, bf16* __restrict__ XS2) {
    int bx = blockIdx.x;               // 32*8*8 = 2048 blocks
    int b  = bx >> 6;
    int tt = (bx >> 3) & 7;
    int kt = bx & 7;
    __shared__ float tile[64][65];
    int tid  = threadIdx.x;
    int row2 = tid >> 6;   // 0..3
    int col  = tid & 63;
#pragma unroll
    for (int i = 0; i < 16; ++i) {
        int row = i * 4 + row2;            // k-local
        int k = kt * 64 + row;
        tile[row][col] = x[((b * 32 + (k >> 4)) * 16 + (k & 15)) * 512 + tt * 64 + col];
    }
    __syncthreads();
#pragma unroll
    for (int i = 0; i < 16; ++i) {
        int trow = i * 4 + row2;           // t-local
        int t = tt * 64 + trow;
        XS2[(t * 32 + b) * 512 + kt * 64 + col] = __float2bfloat16(tile[col][trow]);
    }
}

// ---------------- pack weights / bias / zero-init ----------------
__global__ void pack_w_kernel(const float* __restrict__ Wih_f, const float* __restrict__ Whh_f,
                              const float* __restrict__ bih_f, const float* __restrict__ bhh_f,
                              const float* __restrict__ Wih_b, const float* __restrict__ Whh_b,
                              const float* __restrict__ bih_b, const float* __restrict__ bhh_b,
                              bf16* __restrict__ Wcat, bf16* __restrict__ Whhp,
                              float* __restrict__ bias, unsigned int* __restrict__ hbuf32,
                              unsigned int* __restrict__ ctr) {
    long idx = (long)blockIdx.x * 256 + threadIdx.x;
    if (idx < 262144) {                       // Wcat, 8-wide
        long e = idx * 8;
        int m = (int)(e >> 9), k = (int)(e & 511);
        const float* src = (m < 2048) ? &Wih_f[(long)m * 512 + k]
                                      : &Wih_b[(long)(m - 2048) * 512 + k];
        bf16* dst = &Wcat[e];
#pragma unroll
        for (int j = 0; j < 8; ++j) dst[j] = __float2bfloat16(src[j]);
        return;
    }
    idx -= 262144;
    if (idx < 262144) {                       // Whhp, 8-wide
        long e = idx * 8;
        int k  = (int)(e & 511);
        int lm = (int)((e >> 9) & 63);
        int s  = (int)((e >> 15) & 31);
        int dir = (int)(e >> 20);
        int grow = (lm >> 4) * 512 + s * 16 + (lm & 15);
        const float* W = dir ? Whh_b : Whh_f;
        const float* src = &W[(long)grow * 512 + k];
        bf16* dst = &Whhp[e];
#pragma unroll
        for (int j = 0; j < 8; ++j) dst[j] = __float2bfloat16(src[j]);
        return;
    }
    idx -= 262144;
    if (idx < 4096) {                         // bias = b_ih + b_hh
        int dir = (int)(idx >> 11), g = (int)(idx & 2047);
        bias[idx] = (dir ? (bih_b[g] + bhh_b[g]) : (bih_f[g] + bhh_f[g]));
        return;
    }
    idx -= 4096;
    if (idx < 32768) { hbuf32[idx] = 0u; return; }  // zero h ping-pong
    idx -= 32768;
    if (idx < 64) { ctr[idx] = 0u; return; }        // zero barrier counters
}

// ---------------- phase 1: XP = Wcat * XS2^T ----------------
// A = Wcat [m][k] (4096x512), B^T = XS2 [n][k] (16384x512), n = t*32+b
// XP[t][dir][s][gate][ul][b] bf16
__global__ __launch_bounds__(256, 2) void gemm_xp_kernel(const bf16* __restrict__ Wcat,
                                                         const bf16* __restrict__ XS2,
                                                         bf16* __restrict__ XP) {
    int bm = (blockIdx.x & 31) * 128;
    int bn = (blockIdx.x >> 5) * 128;
    __shared__ bf16 lA[128 * 40];   // pitch 40 (pad) -> 2-way bank aliasing only (free)
    __shared__ bf16 lB[128 * 40];
    int tid = threadIdx.x;
    int lane = tid & 63, w = tid >> 6;
    int wm = (w & 1) * 64, wn = (w >> 1) * 64;
    int fr = lane & 15, fq = lane >> 4;
    f32x4 acc[4][4] = {};
    int r = tid >> 2, c = tid & 3;
    for (int kt = 0; kt < 16; ++kt) {
        int k0 = kt * 32;
        *(bf16x8*)&lA[r * 40 + c * 8]        = *(const bf16x8*)&Wcat[(long)(bm + r) * 512 + k0 + c * 8];
        *(bf16x8*)&lA[(r + 64) * 40 + c * 8] = *(const bf16x8*)&Wcat[(long)(bm + r + 64) * 512 + k0 + c * 8];
        *(bf16x8*)&lB[r * 40 + c * 8]        = *(const bf16x8*)&XS2[(long)(bn + r) * 512 + k0 + c * 8];
        *(bf16x8*)&lB[(r + 64) * 40 + c * 8] = *(const bf16x8*)&XS2[(long)(bn + r + 64) * 512 + k0 + c * 8];
        __syncthreads();
        bf16x8 af[4], bfm[4];
#pragma unroll
        for (int i = 0; i < 4; ++i) af[i]  = *(const bf16x8*)&lA[(wm + i * 16 + fr) * 40 + fq * 8];
#pragma unroll
        for (int i = 0; i < 4; ++i) bfm[i] = *(const bf16x8*)&lB[(wn + i * 16 + fr) * 40 + fq * 8];
#pragma unroll
        for (int mi = 0; mi < 4; ++mi)
#pragma unroll
            for (int ni = 0; ni < 4; ++ni)
                acc[mi][ni] = __builtin_amdgcn_mfma_f32_16x16x32_bf16(af[mi], bfm[ni], acc[mi][ni], 0, 0, 0);
        __syncthreads();
    }
    // epilogue: C/D layout col=lane&15, row=(lane>>4)*4+reg
#pragma unroll
    for (int mi = 0; mi < 4; ++mi) {
#pragma unroll
        for (int rr = 0; rr < 4; ++rr) {
            int m = bm + wm + mi * 16 + fq * 4 + rr;
            int dir = m >> 11, cc = m & 2047;
            int gate = cc >> 9, u = cc & 511, s = u >> 4, ul = u & 15;
#pragma unroll
            for (int ni = 0; ni < 4; ++ni) {
                int n = bn + wn + ni * 16 + fr;
                int t = n >> 5, b = n & 31;
                long off = ((((long)(t * 2 + dir) * 32 + s) * 4 + gate) * 16 + ul) * 32 + b;
                XP[off] = __float2bfloat16(acc[mi][ni][rr]);
            }
        }
    }
}

// ---------------- phase 2: bidirectional LSTM recurrence ----------------
// 64 blocks (dir, s) x 512 threads. W_hh fragments persistent in registers.
// h ping-pong in global (bf16), per-direction monotonic counter barrier.
__global__ __launch_bounds__(512, 2) void lstm_rec_kernel(const bf16* __restrict__ Whhp,
                                                          const bf16* __restrict__ XP,
                                                          const float* __restrict__ bias,
                                                          bf16* hbuf, float* out,
                                                          unsigned int* ctr) {
    int bx = blockIdx.x;
    int dir = bx >> 5, s = bx & 31;
    int tid = threadIdx.x;
    int lane = tid & 63, w = tid >> 6;      // 8 waves
    int mt = w & 3, nt = w >> 2;            // wave -> (gate-row tile, batch half)
    int fr = lane & 15, fq = lane >> 4;
    __shared__ float gbuf[64 * 32];

    // persistent A fragments: Whhp[dir][s][mt*16+fr][k]
    const bf16* wbase = Whhp + ((long)((dir * 32 + s) * 64 + mt * 16 + fr)) * 512 + fq * 8;
    bf16x8 wA[16];
#pragma unroll
    for (int kt = 0; kt < 16; ++kt) wA[kt] = *(const bf16x8*)(wbase + kt * 32);

    // gate-math cell mapping
    int b = tid & 31, ul = (tid >> 5) & 15;
    float bias_i = bias[dir * 2048 + 0 * 512 + s * 16 + ul];
    float bias_f = bias[dir * 2048 + 1 * 512 + s * 16 + ul];
    float bias_g = bias[dir * 2048 + 2 * 512 + s * 16 + ul];
    float bias_o = bias[dir * 2048 + 3 * 512 + s * 16 + ul];
    float cstate = 0.f;
    unsigned int* myctr = ctr + dir * 32;   // 128 B apart
    bf16* hb_dir = hbuf + (long)dir * 2 * BATCH * HID;
    int guard_budget = 1 << 21;             // converts pathological deadlock -> finite

    for (int t = 0; t < TLEN; ++t) {
        int ttime = dir ? (TLEN - 1 - t) : t;
        // xp loads: independent of barrier -> issue early
        const bf16* xpp = XP + (long)(ttime * 2 + dir) * 65536 + (long)s * 2048;
        float xi = __bfloat162float(xpp[(0 * 16 + ul) * 32 + b]);
        float xf = __bfloat162float(xpp[(1 * 16 + ul) * 32 + b]);
        float xg = __bfloat162float(xpp[(2 * 16 + ul) * 32 + b]);
        float xo = __bfloat162float(xpp[(3 * 16 + ul) * 32 + b]);

        if (t > 0) {
            if (tid == 0) {
                unsigned int target = (unsigned int)(32 * t);
                while (__hip_atomic_load(myctr, __ATOMIC_ACQUIRE, __HIP_MEMORY_SCOPE_AGENT) < target) {
                    __builtin_amdgcn_s_sleep(1);
                    if (--guard_budget <= 0) break;
                }
                __threadfence();
            }
            __syncthreads();
        }

        // B fragments: h[b][k] bf16, b = nt*16+fr
        const bf16* hb = hb_dir + (long)(t & 1) * BATCH * HID + (long)(nt * 16 + fr) * 512 + fq * 8;
        bf16x8 hB[16];
#pragma unroll
        for (int kt = 0; kt < 16; ++kt) hB[kt] = *(const bf16x8*)(hb + kt * 32);
        f32x4 acc = {};
#pragma unroll
        for (int kt = 0; kt < 16; ++kt)
            acc = __builtin_amdgcn_mfma_f32_16x16x32_bf16(wA[kt], hB[kt], acc, 0, 0, 0);
#pragma unroll
        for (int rr = 0; rr < 4; ++rr)
            gbuf[(mt * 16 + fq * 4 + rr) * 32 + nt * 16 + fr] = acc[rr];
        __syncthreads();

        float gi = xi + bias_i + gbuf[(0 * 16 + ul) * 32 + b];
        float gf = xf + bias_f + gbuf[(1 * 16 + ul) * 32 + b];
        float gg = xg + bias_g + gbuf[(2 * 16 + ul) * 32 + b];
        float go = xo + bias_o + gbuf[(3 * 16 + ul) * 32 + b];
        float si = sigmoid_fast(gi), sf = sigmoid_fast(gf), so = sigmoid_fast(go);
        cstate = sf * cstate + si * tanh_fast(gg);
        float h = so * tanh_fast(cstate);

        hb_dir[(long)((t + 1) & 1) * BATCH * HID + (long)b * 512 + s * 16 + ul] = __float2bfloat16(h);
        out[(long)b * 524288 + (long)(dir * 512 + s * 16 + ul) * 512 + ttime] = h;

        __syncthreads();   // h + out stores drained (vmcnt(0) before s_barrier)
        if (tid == 0) {
            __threadfence();
            __hip_atomic_fetch_add(myctr, 1u, __ATOMIC_RELEASE, __HIP_MEMORY_SCOPE_AGENT);
        }
    }
}

extern "C" void kernel_launch(void* const* d_in, const int* in_sizes, int n_in,
                              void* d_out, int out_size, void* d_ws, size_t ws_size,
                              hipStream_t stream) {
    const float* x     = (const float*)d_in[0];
    const float* Wih_f = (const float*)d_in[1];
    const float* Whh_f = (const float*)d_in[2];
    const float* bih_f = (const float*)d_in[3];
    const float* bhh_f = (const float*)d_in[4];
    const float* Wih_b = (const float*)d_in[5];
    const float* Whh_b = (const float*)d_in[6];
    const float* bih_b = (const float*)d_in[7];
    const float* bhh_b = (const float*)d_in[8];
    float* out = (float*)d_out;

    if (ws_size < WS_REQUIRED) {
        // Diagnosable failure: absmax ~12345 means "workspace too small",
        // distinguishing it from any logic error (absmax ~0.71).
        ws_too_small_kernel<<<1, 64, 0, stream>>>(out);
        return;
    }

    char* ws = (char*)d_ws;
    bf16* XS2  = (bf16*)(ws + OFF_XS2);
    bf16* Wcat = (bf16*)(ws + OFF_WCAT);
    bf16* Whhp = (bf16*)(ws + OFF_WHHP);
    float* bias = (float*)(ws + OFF_BIAS);
    bf16* hbuf = (bf16*)(ws + OFF_HBUF);
    unsigned int* ctr = (unsigned int*)(ws + OFF_CTR);
    bf16* XP   = (bf16*)(ws + OFF_XP);

    pack_x_kernel<<<2048, 256, 0, stream>>>(x, XS2);
    pack_w_kernel<<<2193, 256, 0, stream>>>(Wih_f, Whh_f, bih_f, bhh_f,
                                            Wih_b, Whh_b, bih_b, bhh_b,
                                            Wcat, Whhp, bias, (unsigned int*)hbuf, ctr);
    gemm_xp_kernel<<<4096, 256, 0, stream>>>(Wcat, XS2, XP);
    lstm_rec_kernel<<<64, 512, 0, stream>>>(Whhp, XP, bias, hbuf, out, ctr);
}

// Round 3
// 5354.362 us; speedup vs baseline: 1.0485x; 1.0485x over previous
//
#include <hip/hip_runtime.h>
#include <hip/hip_bf16.h>

// Problem constants
#define BATCH 32
#define TLEN 512
#define INCH 512
#define HID 512

typedef __bf16 bf16x8 __attribute__((ext_vector_type(8)));
typedef float f32x4 __attribute__((ext_vector_type(4)));
typedef float f32x4v __attribute__((ext_vector_type(4)));
using bf16 = __hip_bfloat16;

// ---------------- ws layout (bytes) ----------------
#define OFF_XS2   0ull                      // 16384*512*2 = 16 MiB
#define OFF_WCAT  16777216ull               // 4096*512*2  = 4 MiB
#define OFF_WHHP  20971520ull               // 2*2048*512*2 = 4 MiB
#define OFF_BIAS  25165824ull               // 2*2048*4 = 16 KiB
#define OFF_HBUF  25182208ull               // 2dir*2buf*32*512*2 = 128 KiB
#define OFF_CTR   25313280ull               // 256 B (legacy, unused)
#define OFF_FLAG  25313536ull               // 64 flags * 128 B = 8 KiB
#define OFF_XP    25321728ull               // 512*2*2048*32*2 = 128 MiB
#define WS_REQUIRED (25321728ull + 134217728ull)

__device__ __forceinline__ float sigmoid_fast(float x) {
    return 1.f / (1.f + __expf(-x));
}
__device__ __forceinline__ float tanh_fast(float x) {
    float ax = fabsf(x);
    float e = __expf(-2.f * ax);
    float r = (1.f - e) / (1.f + e);
    return copysignf(r, x);
}

__global__ void ws_too_small_kernel(float* out) {
    if (threadIdx.x == 0 && blockIdx.x == 0) out[0] = 12345.0f;
}

// ---------------- pack x -> XS2[(t*32+b)][k] bf16 ----------------
__global__ void pack_x_kernel(const float* __restrict__ x, bf16* __restrict__ XS2) {
    int bx = blockIdx.x;               // 2048 blocks
    int b  = bx >> 6;
    int tt = (bx >> 3) & 7;
    int kt = bx & 7;
    __shared__ float tile[64][65];
    int tid  = threadIdx.x;
    int row2 = tid >> 6;
    int col  = tid & 63;
#pragma unroll
    for (int i = 0; i < 16; ++i) {
        int row = i * 4 + row2;
        int k = kt * 64 + row;
        tile[row][col] = x[((b * 32 + (k >> 4)) * 16 + (k & 15)) * 512 + tt * 64 + col];
    }
    __syncthreads();
#pragma unroll
    for (int i = 0; i < 16; ++i) {
        int trow = i * 4 + row2;
        int t = tt * 64 + trow;
        XS2[(t * 32 + b) * 512 + kt * 64 + col] = __float2bfloat16(tile[col][trow]);
    }
}

// ---------------- pack weights / bias / zero-init ----------------
__global__ void pack_w_kernel(const float* __restrict__ Wih_f, const float* __restrict__ Whh_f,
                              const float* __restrict__ bih_f, const float* __restrict__ bhh_f,
                              const float* __restrict__ Wih_b, const float* __restrict__ Whh_b,
                              const float* __restrict__ bih_b, const float* __restrict__ bhh_b,
                              bf16* __restrict__ Wcat, bf16* __restrict__ Whhp,
                              float* __restrict__ bias, unsigned int* __restrict__ hbuf32,
                              unsigned int* __restrict__ ctr, unsigned int* __restrict__ flags) {
    long idx = (long)blockIdx.x * 256 + threadIdx.x;
    if (idx < 262144) {                       // Wcat, 8-wide
        long e = idx * 8;
        int m = (int)(e >> 9), k = (int)(e & 511);
        const float* src = (m < 2048) ? &Wih_f[(long)m * 512 + k]
                                      : &Wih_b[(long)(m - 2048) * 512 + k];
        bf16* dst = &Wcat[e];
#pragma unroll
        for (int j = 0; j < 8; ++j) dst[j] = __float2bfloat16(src[j]);
        return;
    }
    idx -= 262144;
    if (idx < 262144) {                       // Whhp, 8-wide
        long e = idx * 8;
        int k  = (int)(e & 511);
        int lm = (int)((e >> 9) & 63);
        int s  = (int)((e >> 15) & 31);
        int dir = (int)(e >> 20);
        int grow = (lm >> 4) * 512 + s * 16 + (lm & 15);
        const float* W = dir ? Whh_b : Whh_f;
        const float* src = &W[(long)grow * 512 + k];
        bf16* dst = &Whhp[e];
#pragma unroll
        for (int j = 0; j < 8; ++j) dst[j] = __float2bfloat16(src[j]);
        return;
    }
    idx -= 262144;
    if (idx < 4096) {                         // bias = b_ih + b_hh
        int dir = (int)(idx >> 11), g = (int)(idx & 2047);
        bias[idx] = (dir ? (bih_b[g] + bhh_b[g]) : (bih_f[g] + bhh_f[g]));
        return;
    }
    idx -= 4096;
    if (idx < 32768) { hbuf32[idx] = 0u; return; }  // zero h ping-pong
    idx -= 32768;
    if (idx < 64) { ctr[idx] = 0u; return; }
    idx -= 64;
    if (idx < 2048) { flags[idx] = 0u; return; }    // zero epoch flags
}

// ---------------- phase 1: XP = Wcat * XS2^T ----------------
// XP[t][dir][s][gate][ul][b] bf16
__global__ __launch_bounds__(256, 2) void gemm_xp_kernel(const bf16* __restrict__ Wcat,
                                                         const bf16* __restrict__ XS2,
                                                         bf16* __restrict__ XP) {
    int bm = (blockIdx.x & 31) * 128;
    int bn = (blockIdx.x >> 5) * 128;
    __shared__ bf16 lA[128 * 40];
    __shared__ bf16 lB[128 * 40];
    int tid = threadIdx.x;
    int lane = tid & 63, w = tid >> 6;
    int wm = (w & 1) * 64, wn = (w >> 1) * 64;
    int fr = lane & 15, fq = lane >> 4;
    f32x4 acc[4][4] = {};
    int r = tid >> 2, c = tid & 3;
    for (int kt = 0; kt < 16; ++kt) {
        int k0 = kt * 32;
        *(bf16x8*)&lA[r * 40 + c * 8]        = *(const bf16x8*)&Wcat[(long)(bm + r) * 512 + k0 + c * 8];
        *(bf16x8*)&lA[(r + 64) * 40 + c * 8] = *(const bf16x8*)&Wcat[(long)(bm + r + 64) * 512 + k0 + c * 8];
        *(bf16x8*)&lB[r * 40 + c * 8]        = *(const bf16x8*)&XS2[(long)(bn + r) * 512 + k0 + c * 8];
        *(bf16x8*)&lB[(r + 64) * 40 + c * 8] = *(const bf16x8*)&XS2[(long)(bn + r + 64) * 512 + k0 + c * 8];
        __syncthreads();
        bf16x8 af[4], bfm[4];
#pragma unroll
        for (int i = 0; i < 4; ++i) af[i]  = *(const bf16x8*)&lA[(wm + i * 16 + fr) * 40 + fq * 8];
#pragma unroll
        for (int i = 0; i < 4; ++i) bfm[i] = *(const bf16x8*)&lB[(wn + i * 16 + fr) * 40 + fq * 8];
#pragma unroll
        for (int mi = 0; mi < 4; ++mi)
#pragma unroll
            for (int ni = 0; ni < 4; ++ni)
                acc[mi][ni] = __builtin_amdgcn_mfma_f32_16x16x32_bf16(af[mi], bfm[ni], acc[mi][ni], 0, 0, 0);
        __syncthreads();
    }
#pragma unroll
    for (int mi = 0; mi < 4; ++mi) {
#pragma unroll
        for (int rr = 0; rr < 4; ++rr) {
            int m = bm + wm + mi * 16 + fq * 4 + rr;
            int dir = m >> 11, cc = m & 2047;
            int gate = cc >> 9, u = cc & 511, s = u >> 4, ul = u & 15;
#pragma unroll
            for (int ni = 0; ni < 4; ++ni) {
                int n = bn + wn + ni * 16 + fr;
                int t = n >> 5, b = n & 31;
                long off = ((((long)(t * 2 + dir) * 32 + s) * 4 + gate) * 16 + ul) * 32 + b;
                XP[off] = __float2bfloat16(acc[mi][ni][rr]);
            }
        }
    }
}

// ---------------- phase 2: bidirectional LSTM recurrence ----------------
// 64 blocks (dir, s) x 512 threads. W_hh fragments persistent in registers.
// Per-block epoch flags (one 128-B line each); h ping-pong in global (bf16).
__global__ __launch_bounds__(512, 2) void lstm_rec_kernel(const bf16* __restrict__ Whhp,
                                                          const bf16* __restrict__ XP,
                                                          const float* __restrict__ bias,
                                                          bf16* hbuf, float* out,
                                                          unsigned int* flags) {
    int bx = blockIdx.x;
    int dir = bx >> 5, s = bx & 31;
    int tid = threadIdx.x;
    int lane = tid & 63, w = tid >> 6;      // 8 waves
    int mt = w & 3, nt = w >> 2;            // wave -> (gate-row tile, batch half)
    int fr = lane & 15, fq = lane >> 4;
    __shared__ float gbuf[64 * 32];         // 8 KiB  gate pre-activations
    __shared__ float obuf[16][512];         // 32 KiB output chunk [tc][ul*32+b]
    __shared__ bf16  hstage[BATCH * 16];    // 1 KiB  h slice [b][ul]

    // persistent A fragments: Whhp[dir][s][mt*16+fr][k]
    const bf16* wbase = Whhp + ((long)((dir * 32 + s) * 64 + mt * 16 + fr)) * 512 + fq * 8;
    bf16x8 wA[16];
#pragma unroll
    for (int kt = 0; kt < 16; ++kt) wA[kt] = *(const bf16x8*)(wbase + kt * 32);

    // gate-math cell mapping: tid = ul*32 + b
    int b = tid & 31, ul = (tid >> 5) & 15;
    float bias_i = bias[dir * 2048 + 0 * 512 + s * 16 + ul];
    float bias_f = bias[dir * 2048 + 1 * 512 + s * 16 + ul];
    float bias_g = bias[dir * 2048 + 2 * 512 + s * 16 + ul];
    float bias_o = bias[dir * 2048 + 3 * 512 + s * 16 + ul];
    float cstate = 0.f;
    bf16* hb_dir = hbuf + (long)dir * 2 * BATCH * HID;
    unsigned int* myflag   = flags + bx * 32;                          // own line
    const unsigned int* pollflag = flags + (dir * 32 + (lane & 31)) * 32;  // peers
    long orow = (long)b * 524288 + (long)(dir * 512 + s * 16 + ul) * 512;
    int guard_budget = 1 << 21;

    for (int t = 0; t < TLEN; ++t) {
        int ttime = dir ? (TLEN - 1 - t) : t;
        // xp prefetch: independent of barrier -> issue before the spin
        const bf16* xpp = XP + (long)(ttime * 2 + dir) * 65536 + (long)s * 2048;
        float xi = __bfloat162float(xpp[(0 * 16 + ul) * 32 + b]);
        float xf = __bfloat162float(xpp[(1 * 16 + ul) * 32 + b]);
        float xg = __bfloat162float(xpp[(2 * 16 + ul) * 32 + b]);
        float xo = __bfloat162float(xpp[(3 * 16 + ul) * 32 + b]);

        if (t > 0) {
            if (w == 0) {   // wave 0 polls all 32 peer flags in parallel
                unsigned int target = (unsigned int)t;
                for (;;) {
                    unsigned int v = __hip_atomic_load(pollflag, __ATOMIC_ACQUIRE,
                                                       __HIP_MEMORY_SCOPE_AGENT);
                    if (__all(v >= target)) break;
                    __builtin_amdgcn_s_sleep(1);
                    if (--guard_budget <= 0) break;
                }
                __threadfence();   // invalidate caches before h loads
            }
            __syncthreads();
        }

        // B fragments: h[b][k] bf16, b_row = nt*16+fr
        const bf16* hb = hb_dir + (long)(t & 1) * BATCH * HID + (long)(nt * 16 + fr) * 512 + fq * 8;
        bf16x8 hB[16];
#pragma unroll
        for (int kt = 0; kt < 16; ++kt) hB[kt] = *(const bf16x8*)(hb + kt * 32);
        f32x4 acc = {};
#pragma unroll
        for (int kt = 0; kt < 16; ++kt)
            acc = __builtin_amdgcn_mfma_f32_16x16x32_bf16(wA[kt], hB[kt], acc, 0, 0, 0);
#pragma unroll
        for (int rr = 0; rr < 4; ++rr)
            gbuf[(mt * 16 + fq * 4 + rr) * 32 + nt * 16 + fr] = acc[rr];
        __syncthreads();

        float gi = xi + bias_i + gbuf[(0 * 16 + ul) * 32 + b];
        float gf = xf + bias_f + gbuf[(1 * 16 + ul) * 32 + b];
        float gg = xg + bias_g + gbuf[(2 * 16 + ul) * 32 + b];
        float go = xo + bias_o + gbuf[(3 * 16 + ul) * 32 + b];
        float si = sigmoid_fast(gi), sf = sigmoid_fast(gf), so = sigmoid_fast(go);
        cstate = sf * cstate + si * tanh_fast(gg);
        float h = so * tanh_fast(cstate);

        hstage[b * 16 + ul] = __float2bfloat16(h);
        obuf[ttime & 15][tid] = h;
        __syncthreads();

        // wave 0: vectorized h store (64 x 16B), then release-post epoch flag
        if (w == 0) {
            int hbb = lane >> 1, half = lane & 1;
            f32x4v hv = *(const f32x4v*)&hstage[hbb * 16 + half * 8];
            *(f32x4v*)(hb_dir + (long)((t + 1) & 1) * BATCH * HID + (long)hbb * 512
                       + s * 16 + half * 8) = hv;
            __threadfence();   // drain h stores + L2 writeback before flag
            if (lane == 0)
                __hip_atomic_store(myflag, (unsigned int)(t + 1), __ATOMIC_RELEASE,
                                   __HIP_MEMORY_SCOPE_AGENT);
        }

        // output flush every 16 steps — AFTER flag post, off the critical path
        if ((t & 15) == 15) {
            int tb = ttime & ~15;
            float vals[16];
#pragma unroll
            for (int c = 0; c < 16; ++c) vals[c] = obuf[c][tid];
            float* op = out + orow + tb;
#pragma unroll
            for (int c4 = 0; c4 < 4; ++c4)
                *(f32x4v*)(op + c4 * 4) = *(f32x4v*)&vals[c4 * 4];
        }
    }
}

extern "C" void kernel_launch(void* const* d_in, const int* in_sizes, int n_in,
                              void* d_out, int out_size, void* d_ws, size_t ws_size,
                              hipStream_t stream) {
    const float* x     = (const float*)d_in[0];
    const float* Wih_f = (const float*)d_in[1];
    const float* Whh_f = (const float*)d_in[2];
    const float* bih_f = (const float*)d_in[3];
    const float* bhh_f = (const float*)d_in[4];
    const float* Wih_b = (const float*)d_in[5];
    const float* Whh_b = (const float*)d_in[6];
    const float* bih_b = (const float*)d_in[7];
    const float* bhh_b = (const float*)d_in[8];
    float* out = (float*)d_out;

    if (ws_size < WS_REQUIRED) {
        ws_too_small_kernel<<<1, 64, 0, stream>>>(out);
        return;
    }

    char* ws = (char*)d_ws;
    bf16* XS2  = (bf16*)(ws + OFF_XS2);
    bf16* Wcat = (bf16*)(ws + OFF_WCAT);
    bf16* Whhp = (bf16*)(ws + OFF_WHHP);
    float* bias = (float*)(ws + OFF_BIAS);
    bf16* hbuf = (bf16*)(ws + OFF_HBUF);
    unsigned int* ctr   = (unsigned int*)(ws + OFF_CTR);
    unsigned int* flags = (unsigned int*)(ws + OFF_FLAG);
    bf16* XP   = (bf16*)(ws + OFF_XP);

    pack_x_kernel<<<2048, 256, 0, stream>>>(x, XS2);
    pack_w_kernel<<<2201, 256, 0, stream>>>(Wih_f, Whh_f, bih_f, bhh_f,
                                            Wih_b, Whh_b, bih_b, bhh_b,
                                            Wcat, Whhp, bias, (unsigned int*)hbuf, ctr, flags);
    gemm_xp_kernel<<<4096, 256, 0, stream>>>(Wcat, XS2, XP);
    lstm_rec_kernel<<<64, 512, 0, stream>>>(Whhp, XP, bias, hbuf, out, flags);
}

// Round 4
// 2044.846 us; speedup vs baseline: 2.7454x; 2.6185x over previous
//
#include <hip/hip_runtime.h>
#include <hip/hip_bf16.h>

// Problem constants
#define BATCH 32
#define TLEN 512
#define INCH 512
#define HID 512

typedef __bf16 bf16x8 __attribute__((ext_vector_type(8)));
typedef float f32x4 __attribute__((ext_vector_type(4)));
using bf16 = __hip_bfloat16;

// ---------------- ws layout (bytes) ----------------
#define OFF_XS2   0ull                      // 16384*512*2 = 16 MiB
#define OFF_WCAT  16777216ull               // 4096*512*2  = 4 MiB
#define OFF_WHHP  20971520ull               // 2*2048*512*2 = 4 MiB
#define OFF_BIAS  25165824ull               // 2*2048*4 = 16 KiB
#define OFF_HBUF  25182208ull               // 2dir*2buf*32*512*2 = 128 KiB
#define OFF_CTR   25313280ull               // 256 B (legacy, unused)
#define OFF_FLAG  25313536ull               // 64 flags * 128 B = 8 KiB
#define OFF_XP    25321728ull               // 512*2*2048*32*2 = 128 MiB
#define WS_REQUIRED (25321728ull + 134217728ull)

__device__ __forceinline__ float sigmoid_fast(float x) {
    return 1.f / (1.f + __expf(-x));
}
__device__ __forceinline__ float tanh_fast(float x) {
    float ax = fabsf(x);
    float e = __expf(-2.f * ax);
    float r = (1.f - e) / (1.f + e);
    return copysignf(r, x);
}

__global__ void ws_too_small_kernel(float* out) {
    if (threadIdx.x == 0 && blockIdx.x == 0) out[0] = 12345.0f;
}

// ---------------- pack x -> XS2[(t*32+b)][k] bf16 ----------------
__global__ void pack_x_kernel(const float* __restrict__ x, bf16* __restrict__ XS2) {
    int bx = blockIdx.x;               // 2048 blocks
    int b  = bx >> 6;
    int tt = (bx >> 3) & 7;
    int kt = bx & 7;
    __shared__ float tile[64][65];
    int tid  = threadIdx.x;
    int row2 = tid >> 6;
    int col  = tid & 63;
#pragma unroll
    for (int i = 0; i < 16; ++i) {
        int row = i * 4 + row2;
        int k = kt * 64 + row;
        tile[row][col] = x[((b * 32 + (k >> 4)) * 16 + (k & 15)) * 512 + tt * 64 + col];
    }
    __syncthreads();
#pragma unroll
    for (int i = 0; i < 16; ++i) {
        int trow = i * 4 + row2;
        int t = tt * 64 + trow;
        XS2[(t * 32 + b) * 512 + kt * 64 + col] = __float2bfloat16(tile[col][trow]);
    }
}

// ---------------- pack weights / bias / zero-init ----------------
__global__ void pack_w_kernel(const float* __restrict__ Wih_f, const float* __restrict__ Whh_f,
                              const float* __restrict__ bih_f, const float* __restrict__ bhh_f,
                              const float* __restrict__ Wih_b, const float* __restrict__ Whh_b,
                              const float* __restrict__ bih_b, const float* __restrict__ bhh_b,
                              bf16* __restrict__ Wcat, bf16* __restrict__ Whhp,
                              float* __restrict__ bias, unsigned int* __restrict__ hbuf32,
                              unsigned int* __restrict__ ctr, unsigned int* __restrict__ flags) {
    long idx = (long)blockIdx.x * 256 + threadIdx.x;
    if (idx < 262144) {                       // Wcat, 8-wide
        long e = idx * 8;
        int m = (int)(e >> 9), k = (int)(e & 511);
        const float* src = (m < 2048) ? &Wih_f[(long)m * 512 + k]
                                      : &Wih_b[(long)(m - 2048) * 512 + k];
        bf16* dst = &Wcat[e];
#pragma unroll
        for (int j = 0; j < 8; ++j) dst[j] = __float2bfloat16(src[j]);
        return;
    }
    idx -= 262144;
    if (idx < 262144) {                       // Whhp, 8-wide
        long e = idx * 8;
        int k  = (int)(e & 511);
        int lm = (int)((e >> 9) & 63);
        int s  = (int)((e >> 15) & 31);
        int dir = (int)(e >> 20);
        int grow = (lm >> 4) * 512 + s * 16 + (lm & 15);
        const float* W = dir ? Whh_b : Whh_f;
        const float* src = &W[(long)grow * 512 + k];
        bf16* dst = &Whhp[e];
#pragma unroll
        for (int j = 0; j < 8; ++j) dst[j] = __float2bfloat16(src[j]);
        return;
    }
    idx -= 262144;
    if (idx < 4096) {                         // bias = b_ih + b_hh
        int dir = (int)(idx >> 11), g = (int)(idx & 2047);
        bias[idx] = (dir ? (bih_b[g] + bhh_b[g]) : (bih_f[g] + bhh_f[g]));
        return;
    }
    idx -= 4096;
    if (idx < 32768) { hbuf32[idx] = 0u; return; }  // zero h ping-pong
    idx -= 32768;
    if (idx < 64) { ctr[idx] = 0u; return; }
    idx -= 64;
    if (idx < 2048) { flags[idx] = 0u; return; }    // zero epoch flags
}

// ---------------- phase 1: XP = Wcat * XS2^T ----------------
// XP[t][dir][s][gate][ul][b] bf16
__global__ __launch_bounds__(256, 2) void gemm_xp_kernel(const bf16* __restrict__ Wcat,
                                                         const bf16* __restrict__ XS2,
                                                         bf16* __restrict__ XP) {
    int bm = (blockIdx.x & 31) * 128;
    int bn = (blockIdx.x >> 5) * 128;
    __shared__ bf16 lA[128 * 40];
    __shared__ bf16 lB[128 * 40];
    int tid = threadIdx.x;
    int lane = tid & 63, w = tid >> 6;
    int wm = (w & 1) * 64, wn = (w >> 1) * 64;
    int fr = lane & 15, fq = lane >> 4;
    f32x4 acc[4][4] = {};
    int r = tid >> 2, c = tid & 3;
    for (int kt = 0; kt < 16; ++kt) {
        int k0 = kt * 32;
        *(bf16x8*)&lA[r * 40 + c * 8]        = *(const bf16x8*)&Wcat[(long)(bm + r) * 512 + k0 + c * 8];
        *(bf16x8*)&lA[(r + 64) * 40 + c * 8] = *(const bf16x8*)&Wcat[(long)(bm + r + 64) * 512 + k0 + c * 8];
        *(bf16x8*)&lB[r * 40 + c * 8]        = *(const bf16x8*)&XS2[(long)(bn + r) * 512 + k0 + c * 8];
        *(bf16x8*)&lB[(r + 64) * 40 + c * 8] = *(const bf16x8*)&XS2[(long)(bn + r + 64) * 512 + k0 + c * 8];
        __syncthreads();
        bf16x8 af[4], bfm[4];
#pragma unroll
        for (int i = 0; i < 4; ++i) af[i]  = *(const bf16x8*)&lA[(wm + i * 16 + fr) * 40 + fq * 8];
#pragma unroll
        for (int i = 0; i < 4; ++i) bfm[i] = *(const bf16x8*)&lB[(wn + i * 16 + fr) * 40 + fq * 8];
#pragma unroll
        for (int mi = 0; mi < 4; ++mi)
#pragma unroll
            for (int ni = 0; ni < 4; ++ni)
                acc[mi][ni] = __builtin_amdgcn_mfma_f32_16x16x32_bf16(af[mi], bfm[ni], acc[mi][ni], 0, 0, 0);
        __syncthreads();
    }
#pragma unroll
    for (int mi = 0; mi < 4; ++mi) {
#pragma unroll
        for (int rr = 0; rr < 4; ++rr) {
            int m = bm + wm + mi * 16 + fq * 4 + rr;
            int dir = m >> 11, cc = m & 2047;
            int gate = cc >> 9, u = cc & 511, s = u >> 4, ul = u & 15;
#pragma unroll
            for (int ni = 0; ni < 4; ++ni) {
                int n = bn + wn + ni * 16 + fr;
                int t = n >> 5, b = n & 31;
                long off = ((((long)(t * 2 + dir) * 32 + s) * 4 + gate) * 16 + ul) * 32 + b;
                XP[off] = __float2bfloat16(acc[mi][ni][rr]);
            }
        }
    }
}

// ---------------- phase 2: bidirectional LSTM recurrence ----------------
// 64 blocks (dir, s) x 512 threads. NO fences: h + flags exchanged with
// device-coherent sc0/sc1 accesses (IC is the coherence point); ordering via
// raw s_waitcnt vmcnt(0). h staged once per block into LDS (pitch 520).
__global__ __launch_bounds__(512, 2) void lstm_rec_kernel(const bf16* __restrict__ Whhp,
                                                          const bf16* __restrict__ XP,
                                                          const float* __restrict__ bias,
                                                          bf16* hbuf, float* out,
                                                          unsigned int* flags) {
    int bx = blockIdx.x;
    int dir = bx >> 5, s = bx & 31;
    int tid = threadIdx.x;
    int lane = tid & 63, w = tid >> 6;      // 8 waves
    int mt = w & 3, nt = w >> 2;            // wave -> (gate-row tile, batch half)
    int fr = lane & 15, fq = lane >> 4;
    __shared__ float gbuf[64 * 32];         // 8 KiB  gate pre-activations
    __shared__ float obuf[16][512];         // 32 KiB output chunk
    __shared__ bf16  hstage[BATCH * 16];    // 1 KiB  h slice [b][ul]
    __shared__ bf16  hsh[32 * 520];         // 32.5 KiB staged h [b][k], pitch 520

    // persistent A fragments: Whhp[dir][s][mt*16+fr][k]
    const bf16* wbase = Whhp + ((long)((dir * 32 + s) * 64 + mt * 16 + fr)) * 512 + fq * 8;
    bf16x8 wA[16];
#pragma unroll
    for (int kt = 0; kt < 16; ++kt) wA[kt] = *(const bf16x8*)(wbase + kt * 32);

    // gate-math cell mapping: tid = ul*32 + b
    int b = tid & 31, ul = (tid >> 5) & 15;
    float bias_i = bias[dir * 2048 + 0 * 512 + s * 16 + ul];
    float bias_f = bias[dir * 2048 + 1 * 512 + s * 16 + ul];
    float bias_g = bias[dir * 2048 + 2 * 512 + s * 16 + ul];
    float bias_o = bias[dir * 2048 + 3 * 512 + s * 16 + ul];
    float cstate = 0.f;
    bf16* hb_dir = hbuf + (long)dir * 2 * BATCH * HID;
    unsigned int* myflag = flags + bx * 32;                           // own 128-B line
    const unsigned int* pollflag = flags + (dir * 32 + (lane & 31)) * 32;
    long orow = (long)b * 524288 + (long)(dir * 512 + s * 16 + ul) * 512;
    // staging mapping: thread stages 64 B of h: row = tid>>4, cols colblk*32..+32
    int srow = tid >> 4, scol = (tid & 15) * 32;
    int guard_budget = 1 << 21;

    for (int t = 0; t < TLEN; ++t) {
        int ttime = dir ? (TLEN - 1 - t) : t;
        // xp prefetch (normal cached loads): independent of the wait
        const bf16* xpp = XP + (long)(ttime * 2 + dir) * 65536 + (long)s * 2048;
        float xi = __bfloat162float(xpp[(0 * 16 + ul) * 32 + b]);
        float xf = __bfloat162float(xpp[(1 * 16 + ul) * 32 + b]);
        float xg = __bfloat162float(xpp[(2 * 16 + ul) * 32 + b]);
        float xo = __bfloat162float(xpp[(3 * 16 + ul) * 32 + b]);

        if (t > 0) {
            // every wave polls all 32 peer flags (relaxed: plain sc1 loads,
            // NO buffer_inv / wbl2 cache maintenance)
            unsigned int target = (unsigned int)t;
            for (;;) {
                unsigned int v = __hip_atomic_load(pollflag, __ATOMIC_RELAXED,
                                                   __HIP_MEMORY_SCOPE_AGENT);
                if (__all(v >= target)) break;
                if (--guard_budget <= 0) break;
            }
        }

        // stage h (device-coherent 16-B loads, bypass L1/L2) into LDS
        {
            const bf16* src = hb_dir + (long)(t & 1) * BATCH * HID + (long)srow * 512 + scol;
            f32x4 v0, v1, v2, v3;
            asm volatile(
                "global_load_dwordx4 %0, %4, off sc0 sc1\n\t"
                "global_load_dwordx4 %1, %4, off offset:16 sc0 sc1\n\t"
                "global_load_dwordx4 %2, %4, off offset:32 sc0 sc1\n\t"
                "global_load_dwordx4 %3, %4, off offset:48 sc0 sc1\n\t"
                "s_waitcnt vmcnt(0)"
                : "=v"(v0), "=v"(v1), "=v"(v2), "=v"(v3)
                : "v"(src) : "memory");
            bf16* d = &hsh[srow * 520 + scol];
            *(f32x4*)(d)      = v0;
            *(f32x4*)(d + 8)  = v1;
            *(f32x4*)(d + 16) = v2;
            *(f32x4*)(d + 24) = v3;
        }
        __syncthreads();

        // B fragments from LDS; MFMA over K=512
        f32x4 acc = {};
#pragma unroll
        for (int kt = 0; kt < 16; ++kt) {
            bf16x8 hB = *(const bf16x8*)&hsh[(nt * 16 + fr) * 520 + kt * 32 + fq * 8];
            acc = __builtin_amdgcn_mfma_f32_16x16x32_bf16(wA[kt], hB, acc, 0, 0, 0);
        }
#pragma unroll
        for (int rr = 0; rr < 4; ++rr)
            gbuf[(mt * 16 + fq * 4 + rr) * 32 + nt * 16 + fr] = acc[rr];
        __syncthreads();

        float gi = xi + bias_i + gbuf[(0 * 16 + ul) * 32 + b];
        float gf = xf + bias_f + gbuf[(1 * 16 + ul) * 32 + b];
        float gg = xg + bias_g + gbuf[(2 * 16 + ul) * 32 + b];
        float go = xo + bias_o + gbuf[(3 * 16 + ul) * 32 + b];
        float si = sigmoid_fast(gi), sf = sigmoid_fast(gf), so = sigmoid_fast(go);
        cstate = sf * cstate + si * tanh_fast(gg);
        float h = so * tanh_fast(cstate);

        hstage[b * 16 + ul] = __float2bfloat16(h);
        obuf[ttime & 15][tid] = h;
        __syncthreads();

        // wave 0: device-coherent h store (64 x 16B) -> drain -> relaxed flag post
        if (w == 0) {
            int hbb = lane >> 1, half = lane & 1;
            f32x4 hv = *(const f32x4*)&hstage[hbb * 16 + half * 8];
            bf16* dst = hb_dir + (long)((t + 1) & 1) * BATCH * HID + (long)hbb * 512
                        + s * 16 + half * 8;
            asm volatile("global_store_dwordx4 %0, %1, off sc0 sc1"
                         :: "v"(dst), "v"(hv) : "memory");
            asm volatile("s_waitcnt vmcnt(0)" ::: "memory");
            if (lane == 0)
                __hip_atomic_store(myflag, (unsigned int)(t + 1), __ATOMIC_RELAXED,
                                   __HIP_MEMORY_SCOPE_AGENT);
        }

        // output flush every 16 steps — after flag post, off the critical path
        if ((t & 15) == 15) {
            int tb = ttime & ~15;
            float vals[16];
#pragma unroll
            for (int c = 0; c < 16; ++c) vals[c] = obuf[c][tid];
            float* op = out + orow + tb;
#pragma unroll
            for (int c4 = 0; c4 < 4; ++c4)
                *(f32x4*)(op + c4 * 4) = *(f32x4*)&vals[c4 * 4];
        }
    }
}

extern "C" void kernel_launch(void* const* d_in, const int* in_sizes, int n_in,
                              void* d_out, int out_size, void* d_ws, size_t ws_size,
                              hipStream_t stream) {
    const float* x     = (const float*)d_in[0];
    const float* Wih_f = (const float*)d_in[1];
    const float* Whh_f = (const float*)d_in[2];
    const float* bih_f = (const float*)d_in[3];
    const float* bhh_f = (const float*)d_in[4];
    const float* Wih_b = (const float*)d_in[5];
    const float* Whh_b = (const float*)d_in[6];
    const float* bih_b = (const float*)d_in[7];
    const float* bhh_b = (const float*)d_in[8];
    float* out = (float*)d_out;

    if (ws_size < WS_REQUIRED) {
        ws_too_small_kernel<<<1, 64, 0, stream>>>(out);
        return;
    }

    char* ws = (char*)d_ws;
    bf16* XS2  = (bf16*)(ws + OFF_XS2);
    bf16* Wcat = (bf16*)(ws + OFF_WCAT);
    bf16* Whhp = (bf16*)(ws + OFF_WHHP);
    float* bias = (float*)(ws + OFF_BIAS);
    bf16* hbuf = (bf16*)(ws + OFF_HBUF);
    unsigned int* ctr   = (unsigned int*)(ws + OFF_CTR);
    unsigned int* flags = (unsigned int*)(ws + OFF_FLAG);
    bf16* XP   = (bf16*)(ws + OFF_XP);

    pack_x_kernel<<<2048, 256, 0, stream>>>(x, XS2);
    pack_w_kernel<<<2201, 256, 0, stream>>>(Wih_f, Whh_f, bih_f, bhh_f,
                                            Wih_b, Whh_b, bih_b, bhh_b,
                                            Wcat, Whhp, bias, (unsigned int*)hbuf, ctr, flags);
    gemm_xp_kernel<<<4096, 256, 0, stream>>>(Wcat, XS2, XP);
    lstm_rec_kernel<<<64, 512, 0, stream>>>(Whhp, XP, bias, hbuf, out, flags);
}